// Round 6
// baseline (195.137 us; speedup 1.0000x reference)
//
#include <hip/hip_runtime.h>
#include <cstddef>

#define NDIM 4096
#define SCALE 0.08838834764831843f
#define SOFT_BIAS 8.0f

typedef _Float16 h8 __attribute__((ext_vector_type(8)));
typedef _Float16 h4 __attribute__((ext_vector_type(4)));
typedef _Float16 h2 __attribute__((ext_vector_type(2)));
typedef float    f4 __attribute__((ext_vector_type(4)));

__device__ __forceinline__ h8 cvt_w_frag(const float* wp) {
    const float4 u0 = *(const float4*)wp;
    const float4 u1 = *(const float4*)(wp + 4);
    h8 f;
    f[0]=(_Float16)u0.x; f[1]=(_Float16)u0.y; f[2]=(_Float16)u0.z; f[3]=(_Float16)u0.w;
    f[4]=(_Float16)u1.x; f[5]=(_Float16)u1.y; f[6]=(_Float16)u1.z; f[7]=(_Float16)u1.w;
    return f;
}

// ---------------- QKV projection: one projection per block, 32-n tiles -------
// Grid (128, 4, 3) = 1536 blocks (~6/CU). W fragments loaded fp32 from global
// and converted in-register (no prep kernel). X staged [n][c] fp16 in LDS.
__global__ __launch_bounds__(256, 2) void proj_qkv_kernel(
    const float* __restrict__ spatial, const float* __restrict__ temporal,
    const float* __restrict__ Wq, const float* __restrict__ Wk,
    const float* __restrict__ Wv,
    const float* __restrict__ bq, const float* __restrict__ bk,
    const float* __restrict__ bv,
    _Float16* __restrict__ Qh, _Float16* __restrict__ Kh, _Float16* __restrict__ Vt)
{
    __shared__ __align__(16) _Float16 Xl[32 * 136];
    const int tid = threadIdx.x;
    const int n0  = blockIdx.x * 32;
    const int b   = blockIdx.y;
    const int p   = blockIdx.z;

    const float* __restrict__ W    = (p == 0) ? Wq : (p == 1) ? Wk : Wv;
    const float* __restrict__ bias = (p == 0) ? bq : (p == 1) ? bk : bv;

    {   // stage X: float4 along contiguous n/hw axis, pack c-pairs -> b32 LDS
        const float* src; size_t rs;
        if (p == 0) { const int t = n0 >> 10, hw0 = n0 & 1023;
            src = spatial + (((size_t)(b * 4 + t) * 128) << 10) + hw0; rs = 1024; }
        else { src = temporal + ((size_t)(b * 128) << 12) + n0; rs = 4096; }
        #pragma unroll
        for (int i = 0; i < 2; ++i) {
            const int ii = tid + 256 * i;          // 512 chunks: c2 = ii>>3, j = ii&7
            const int c2 = ii >> 3, j = ii & 7;
            const float4 v0 = *(const float4*)(src + (size_t)(2 * c2) * rs + 4 * j);
            const float4 v1 = *(const float4*)(src + (size_t)(2 * c2 + 1) * rs + 4 * j);
            const float a0[4] = {v0.x, v0.y, v0.z, v0.w};
            const float a1[4] = {v1.x, v1.y, v1.z, v1.w};
            #pragma unroll
            for (int u = 0; u < 4; ++u) {
                h2 pk; pk[0] = (_Float16)a0[u]; pk[1] = (_Float16)a1[u];
                *(h2*)&Xl[(4 * j + u) * 136 + 2 * c2] = pk;
            }
        }
    }
    __syncthreads();

    const int w = tid >> 6, n16 = tid & 15, q4 = (tid >> 4) & 3;

    // W fragments (rows o = 16*(2w+otl)+n16), fp32 -> fp16 in-register
    h8 wf[2][4];
    #pragma unroll
    for (int otl = 0; otl < 2; ++otl)
        #pragma unroll
        for (int ks = 0; ks < 4; ++ks)
            wf[otl][ks] = cvt_w_frag(W + (size_t)(16 * (2 * w + otl) + n16) * 128
                                       + 32 * ks + 8 * q4);
    h8 xf[2][4];
    #pragma unroll
    for (int ns = 0; ns < 2; ++ns)
        #pragma unroll
        for (int ks = 0; ks < 4; ++ks)
            xf[ns][ks] = *(const h8*)&Xl[(16 * ns + n16) * 136 + 32 * ks + 8 * q4];

    if (p < 2) {
        // D[o][n] = W · X^T
        f4 acc[2][2];
        #pragma unroll
        for (int i = 0; i < 2; ++i) { acc[i][0] = (f4)0.0f; acc[i][1] = (f4)0.0f; }
        #pragma unroll
        for (int otl = 0; otl < 2; ++otl)
            #pragma unroll
            for (int ns = 0; ns < 2; ++ns)
                #pragma unroll
                for (int ks = 0; ks < 4; ++ks)
                    acc[otl][ns] = __builtin_amdgcn_mfma_f32_16x16x32_f16(
                        wf[otl][ks], xf[ns][ks], acc[otl][ns], 0, 0, 0);
        _Float16* __restrict__ dst = (p == 0) ? Qh : Kh;
        #pragma unroll
        for (int otl = 0; otl < 2; ++otl) {
            const float4 bb = *(const float4*)&bias[16 * (2 * w + otl) + 4 * q4];
            #pragma unroll
            for (int ns = 0; ns < 2; ++ns) {
                h4 r;
                r[0]=(_Float16)(acc[otl][ns][0]+bb.x); r[1]=(_Float16)(acc[otl][ns][1]+bb.y);
                r[2]=(_Float16)(acc[otl][ns][2]+bb.z); r[3]=(_Float16)(acc[otl][ns][3]+bb.w);
                *(h4*)(dst + ((size_t)b * NDIM + n0 + 16 * ns + n16) * 128
                           + 16 * (2 * w + otl) + 4 * q4) = r;
            }
        }
    } else {
        // V: D[n][o] = X · W^T, stored transposed -> Vt[b][c][n]
        f4 acc[2][2];
        #pragma unroll
        for (int i = 0; i < 2; ++i) { acc[i][0] = (f4)0.0f; acc[i][1] = (f4)0.0f; }
        #pragma unroll
        for (int ns = 0; ns < 2; ++ns)
            #pragma unroll
            for (int otl = 0; otl < 2; ++otl)
                #pragma unroll
                for (int ks = 0; ks < 4; ++ks)
                    acc[ns][otl] = __builtin_amdgcn_mfma_f32_16x16x32_f16(
                        xf[ns][ks], wf[otl][ks], acc[ns][otl], 0, 0, 0);
        #pragma unroll
        for (int ns = 0; ns < 2; ++ns)
            #pragma unroll
            for (int otl = 0; otl < 2; ++otl) {
                const float bb = bias[16 * (2 * w + otl) + n16];
                h4 r;
                r[0]=(_Float16)(acc[ns][otl][0]+bb); r[1]=(_Float16)(acc[ns][otl][1]+bb);
                r[2]=(_Float16)(acc[ns][otl][2]+bb); r[3]=(_Float16)(acc[ns][otl][3]+bb);
                *(h4*)(Vt + ((size_t)(b * 128 + 16 * (2 * w + otl) + n16) << 12)
                          + n0 + 16 * ns + 4 * q4) = r;
            }
    }
}

// ---------------- flash attention: 256 thr, 128 Q-rows, m-tile 64 -------------
// 4 waves = 2 groups (q64) x 2 (p): S splits m (32/32), PV splits c (64/64).
// 16 iters, 3 barriers/iter. Grid (32,4,4) = 512 = 2 blocks/CU.
__global__ __launch_bounds__(256, 2) void attn_kernel(
    const _Float16* __restrict__ Qh, const _Float16* __restrict__ Kh,
    const _Float16* __restrict__ Vt, _Float16* __restrict__ Opart,
    float* __restrict__ lpart)
{
    // Kt[64][136] | Vl[128][72] | P[2][64][72]  = 27136 h16 = 54.3 KB
    __shared__ __align__(16) _Float16 sh[27136];
    _Float16* __restrict__ Kt = sh;             // 8704
    _Float16* __restrict__ Vl = sh + 8704;      // 9216
    _Float16* __restrict__ Pa = sh + 17920;     // 9216

    const int tid  = threadIdx.x;
    const int w    = tid >> 6, lane = tid & 63;
    const int g    = w >> 1,  p    = w & 1;
    const int n16  = lane & 15, q4 = lane >> 4;
    const int b    = blockIdx.z, hf = blockIdx.y;
    const int n0   = blockIdx.x * 128;
    const int mb   = hf * 1024;

    _Float16* __restrict__ Pg = Pa + g * 4608;

    // Q B-frags: group's q64 (4 strips of 16)
    h8 qf[4][4];
    {
        const _Float16* Qb = Qh + ((size_t)b * NDIM + n0 + 64 * g + n16) * 128;
        #pragma unroll
        for (int qs = 0; qs < 4; ++qs)
            #pragma unroll
            for (int ks = 0; ks < 4; ++ks)
                qf[qs][ks] = *(const h8*)(Qb + (size_t)(16 * qs) * 128 + 32 * ks + 8 * q4);
    }

    // staging: K 64x128 (4 int4/thr), V 128x64 (4 int4/thr)
    const int km  = tid >> 2, kc8 = (tid & 3) * 32;
    const int vc  = tid >> 1, vm8 = (tid & 1) * 32;
    const _Float16* kp = Kh + ((size_t)b * NDIM + mb + km) * 128 + kc8;
    const _Float16* vp = Vt + (((size_t)(b * 128 + vc)) << 12) + mb + vm8;
    int4 kreg[4], vreg[4];
    #pragma unroll
    for (int j = 0; j < 4; ++j) {
        kreg[j] = *(const int4*)(kp + 8 * j);
        vreg[j] = *(const int4*)(vp + 8 * j);
    }

    f4 oacc[4][4];
    #pragma unroll
    for (int i = 0; i < 4; ++i)
        #pragma unroll
        for (int j = 0; j < 4; ++j) oacc[i][j] = (f4)0.0f;
    float lsum[4] = {0.0f, 0.0f, 0.0f, 0.0f};

    for (int it = 0; it < 16; ++it) {
        __syncthreads();                                 // prior tile/P reads done
        #pragma unroll
        for (int j = 0; j < 4; ++j) {
            *(int4*)&Kt[km * 136 + kc8 + 8 * j] = kreg[j];
            *(int4*)&Vl[vc * 72  + vm8 + 8 * j] = vreg[j];
        }
        __syncthreads();                                 // tile visible

        if (it < 15) {                                   // prefetch next tile
            kp += 64 * 128; vp += 64;
            #pragma unroll
            for (int j = 0; j < 4; ++j) {
                kreg[j] = *(const int4*)(kp + 8 * j);
                vreg[j] = *(const int4*)(vp + 8 * j);
            }
        }

        // ---- S^T: wave (g,p): q64 x m32 (m-half p). A=K rows m, B=Q cols q.
        #pragma unroll
        for (int mt2 = 0; mt2 < 2; ++mt2) {
            f4 s[4];
            #pragma unroll
            for (int qs = 0; qs < 4; ++qs) s[qs] = (f4)0.0f;
            #pragma unroll
            for (int ks = 0; ks < 4; ++ks) {
                const h8 kf = *(const h8*)&Kt[(16 * (2 * p + mt2) + n16) * 136
                                              + 32 * ks + 8 * q4];
                #pragma unroll
                for (int qs = 0; qs < 4; ++qs)
                    s[qs] = __builtin_amdgcn_mfma_f32_16x16x32_f16(kf, qf[qs][ks], s[qs], 0, 0, 0);
            }
            // P = exp(S*scale - 8): col q = 16qs+n16, row m = 32p+16mt2+4q4+r
            #pragma unroll
            for (int qs = 0; qs < 4; ++qs) {
                h4 pk;
                #pragma unroll
                for (int r = 0; r < 4; ++r) {
                    const float e = __expf(fmaf(s[qs][r], SCALE, -SOFT_BIAS));
                    lsum[qs] += e;
                    pk[r] = (_Float16)e;
                }
                *(h4*)&Pg[(16 * qs + n16) * 72 + 32 * p + 16 * mt2 + 4 * q4] = pk;
            }
        }
        __syncthreads();                                 // P complete (cross-pair)

        // ---- O += P·V: wave (g,p): q64 x c64 (c-half p), k = m64 (2 chunks)
        #pragma unroll
        for (int kk = 0; kk < 2; ++kk) {
            h8 pf[4], vf[4];
            #pragma unroll
            for (int qs = 0; qs < 4; ++qs)
                pf[qs] = *(const h8*)&Pg[(16 * qs + n16) * 72 + 32 * kk + 8 * q4];
            #pragma unroll
            for (int ct = 0; ct < 4; ++ct)
                vf[ct] = *(const h8*)&Vl[(64 * p + 16 * ct + n16) * 72 + 32 * kk + 8 * q4];
            #pragma unroll
            for (int qs = 0; qs < 4; ++qs)
                #pragma unroll
                for (int ct = 0; ct < 4; ++ct)
                    oacc[qs][ct] = __builtin_amdgcn_mfma_f32_16x16x32_f16(
                        pf[qs], vf[ct], oacc[qs][ct], 0, 0, 0);
        }
    }

    // ---- l: reduce q4 replicas; store per-(hf,p) partial (summed in final proj)
    #pragma unroll
    for (int qs = 0; qs < 4; ++qs) {
        lsum[qs] += __shfl_xor(lsum[qs], 16, 64);
        lsum[qs] += __shfl_xor(lsum[qs], 32, 64);
    }
    if (q4 == 0) {
        float* lb = lpart + ((size_t)((hf * 2 + p) * 4 + b)) * NDIM + n0 + 64 * g;
        #pragma unroll
        for (int qs = 0; qs < 4; ++qs) lb[16 * qs + n16] = lsum[qs];
    }

    // ---- epilogue: transpose all 128 rows via LDS (reuse sh), 2 barriers
    __syncthreads();                                     // all PV frag reads done
    #pragma unroll
    for (int qs = 0; qs < 4; ++qs)
        #pragma unroll
        for (int ct = 0; ct < 4; ++ct)
            #pragma unroll
            for (int r = 0; r < 4; ++r)
                sh[(64 * g + 16 * qs + 4 * q4 + r) * 136 + 64 * p + 16 * ct + n16] =
                    (_Float16)oacc[qs][ct][r];
    __syncthreads();
    const size_t ob = ((size_t)(hf * 4 + b) * NDIM + n0) * 128;
    #pragma unroll
    for (int i = 0; i < 8; ++i) {
        const int ii  = tid + 256 * i;                   // 2048 int4 (128 rows x 16)
        const int row = ii >> 4, c8 = (ii & 15) * 8;
        *(int4*)(Opart + ob + (size_t)row * 128 + c8) = *(const int4*)&sh[row * 136 + c8];
    }
}

// ---------------- final projection: merge 8 partials, /l, Wo, out[b][c][n] ----
// Grid (128, 4) = 512 blocks, 32-n tiles. Wo fragments fp32->fp16 in-register.
__global__ __launch_bounds__(256, 2) void proj_final_kernel(
    const _Float16* __restrict__ Opart, const float* __restrict__ lpart,
    const float* __restrict__ Wo, const float* __restrict__ bo,
    float* __restrict__ out)
{
    __shared__ __align__(16) _Float16 Xl[32 * 136];
    __shared__ float lrow[32];
    __shared__ __align__(16) float Ofin[128 * 36];
    const int tid = threadIdx.x;
    const int n0  = blockIdx.x * 32;
    const int b   = blockIdx.y;

    if (tid < 32) {
        float l = 0.0f;
        #pragma unroll
        for (int h8i = 0; h8i < 8; ++h8i)
            l += lpart[((size_t)(h8i * 4 + b)) * NDIM + n0 + tid];
        lrow[tid] = 1.0f / l;
    }
    // O-sum into registers (512 h8-chunks: 32 rows x 16)
    float vals[2][8];
    int rows[2], c8s[2];
    #pragma unroll
    for (int i = 0; i < 2; ++i) {
        const int ii = tid + 256 * i;
        rows[i] = ii >> 4; c8s[i] = (ii & 15) * 8;
        #pragma unroll
        for (int j = 0; j < 8; ++j) vals[i][j] = 0.0f;
        #pragma unroll
        for (int hf = 0; hf < 4; ++hf) {
            const h8 o = *(const h8*)(Opart + ((size_t)(hf * 4 + b) * NDIM + n0 + rows[i]) * 128
                                      + c8s[i]);
            #pragma unroll
            for (int j = 0; j < 8; ++j) vals[i][j] += (float)o[j];
        }
    }
    __syncthreads();
    #pragma unroll
    for (int i = 0; i < 2; ++i) {
        const float linv = lrow[rows[i]];
        h8 r;
        #pragma unroll
        for (int j = 0; j < 8; ++j) r[j] = (_Float16)(vals[i][j] * linv);
        *(h8*)&Xl[rows[i] * 136 + c8s[i]] = r;
    }
    __syncthreads();

    const int w = tid >> 6, n16 = tid & 15, q4 = (tid >> 4) & 3;

    h8 wf[2][4];
    #pragma unroll
    for (int otl = 0; otl < 2; ++otl)
        #pragma unroll
        for (int ks = 0; ks < 4; ++ks)
            wf[otl][ks] = cvt_w_frag(Wo + (size_t)(16 * (2 * w + otl) + n16) * 128
                                        + 32 * ks + 8 * q4);
    h8 xf[2][4];
    #pragma unroll
    for (int ns = 0; ns < 2; ++ns)
        #pragma unroll
        for (int ks = 0; ks < 4; ++ks)
            xf[ns][ks] = *(const h8*)&Xl[(16 * ns + n16) * 136 + 32 * ks + 8 * q4];

    f4 acc[2][2];
    #pragma unroll
    for (int i = 0; i < 2; ++i) { acc[i][0] = (f4)0.0f; acc[i][1] = (f4)0.0f; }
    #pragma unroll
    for (int otl = 0; otl < 2; ++otl)
        #pragma unroll
        for (int ns = 0; ns < 2; ++ns)
            #pragma unroll
            for (int ks = 0; ks < 4; ++ks)
                acc[otl][ns] = __builtin_amdgcn_mfma_f32_16x16x32_f16(
                    wf[otl][ks], xf[ns][ks], acc[otl][ns], 0, 0, 0);

    // D[o][n] -> Ofin (fp32, +bias), then coalesced float4 stores (128B runs)
    #pragma unroll
    for (int otl = 0; otl < 2; ++otl) {
        const float4 bb = *(const float4*)&bo[16 * (2 * w + otl) + 4 * q4];
        const float bias[4] = {bb.x, bb.y, bb.z, bb.w};
        #pragma unroll
        for (int ns = 0; ns < 2; ++ns)
            #pragma unroll
            for (int r = 0; r < 4; ++r)
                Ofin[(16 * (2 * w + otl) + 4 * q4 + r) * 36 + 16 * ns + n16] =
                    acc[otl][ns][r] + bias[r];
    }
    __syncthreads();
    #pragma unroll
    for (int i = 0; i < 4; ++i) {
        const int ii  = tid + 256 * i;                   // 1024 float4 (128 rows x 8)
        const int row = ii >> 3, j = ii & 7;
        *(float4*)(out + (((size_t)(b * 128 + row)) << 12) + n0 + 4 * j) =
            *(const float4*)&Ofin[row * 36 + 4 * j];
    }
}

extern "C" void kernel_launch(void* const* d_in, const int* in_sizes, int n_in,
                              void* d_out, int out_size, void* d_ws, size_t ws_size,
                              hipStream_t stream)
{
    const float* spatial  = (const float*)d_in[0];
    const float* temporal = (const float*)d_in[1];
    const float* Wq = (const float*)d_in[2];
    const float* bq = (const float*)d_in[3];
    const float* Wk = (const float*)d_in[4];
    const float* bk = (const float*)d_in[5];
    const float* Wv = (const float*)d_in[6];
    const float* bv = (const float*)d_in[7];
    const float* Wo = (const float*)d_in[8];
    const float* bo = (const float*)d_in[9];

    char* ws = (char*)d_ws;                               // 28.5 MB total
    _Float16* Qh    = (_Float16*)(ws);                    //  4 MB [b][n][c]
    _Float16* Kh    = (_Float16*)(ws + (4u  << 20));      //  4 MB [b][n][c]
    _Float16* Vt    = (_Float16*)(ws + (8u  << 20));      //  4 MB [b][c][n]
    _Float16* Opart = (_Float16*)(ws + (12u << 20));      // 16 MB [hf][b][n][c]
    float*    lpart = (float*)   (ws + (28u << 20));      // 512 KB [hf*2+p][b][n]

    proj_qkv_kernel<<<dim3(128, 4, 3), 256, 0, stream>>>(
        spatial, temporal, Wq, Wk, Wv, bq, bk, bv, Qh, Kh, Vt);
    attn_kernel<<<dim3(32, 4, 4), 256, 0, stream>>>(Qh, Kh, Vt, Opart, lpart);
    proj_final_kernel<<<dim3(128, 4), 256, 0, stream>>>(Opart, lpart, Wo, bo,
                                                        (float*)d_out);
}

// Round 8
// 138.125 us; speedup vs baseline: 1.4128x; 1.4128x over previous
//
#include <hip/hip_runtime.h>
#include <cstddef>

#define NDIM 4096
#define SCALE 0.08838834764831843f
#define SOFT_BIAS 8.0f

typedef _Float16 h8 __attribute__((ext_vector_type(8)));
typedef _Float16 h4 __attribute__((ext_vector_type(4)));
typedef _Float16 h2 __attribute__((ext_vector_type(2)));
typedef float    f4 __attribute__((ext_vector_type(4)));

__device__ __forceinline__ h8 cvt_w_frag(const float* wp) {
    const float4 u0 = *(const float4*)wp;
    const float4 u1 = *(const float4*)(wp + 4);
    h8 f;
    f[0]=(_Float16)u0.x; f[1]=(_Float16)u0.y; f[2]=(_Float16)u0.z; f[3]=(_Float16)u0.w;
    f[4]=(_Float16)u1.x; f[5]=(_Float16)u1.y; f[6]=(_Float16)u1.z; f[7]=(_Float16)u1.w;
    return f;
}

// ---------------- weights fp32 -> fp16 in MFMA-FRAGMENT order -----------------
// Whf[mat][ot][ks][lane] (8 h16 each): proj W-loads become one coalesced
// 1KB b128 per wave. frag source: W row 16ot+(lane&15), cols 32ks+8*(lane>>4).
__global__ __launch_bounds__(256) void prep_w_kernel(
    const float* __restrict__ Wq, const float* __restrict__ Wk,
    const float* __restrict__ Wv, const float* __restrict__ Wo,
    _Float16* __restrict__ Whf)
{
    const int gid = blockIdx.x * 256 + threadIdx.x;   // grid 32 -> 8192 frags
    const int mat = gid >> 11, rem = gid & 2047;
    const int ot = rem >> 8, ks = (rem >> 6) & 3, l = rem & 63;
    const float* src = mat == 0 ? Wq : mat == 1 ? Wk : mat == 2 ? Wv : Wo;
    const h8 f = cvt_w_frag(src + (size_t)(16 * ot + (l & 15)) * 128 + 32 * ks + 8 * (l >> 4));
    *(h8*)(Whf + (size_t)gid * 8) = f;
}

// ---------------- QKV projection: 32-n tiles, grid (128,4,3) ~ 6 blocks/CU ----
__global__ __launch_bounds__(256, 3) void proj_qkv_kernel(
    const float* __restrict__ spatial, const float* __restrict__ temporal,
    const _Float16* __restrict__ Whf,
    const float* __restrict__ bq, const float* __restrict__ bk,
    const float* __restrict__ bv,
    _Float16* __restrict__ Qh, _Float16* __restrict__ Kh, _Float16* __restrict__ Vt)
{
    __shared__ __align__(16) _Float16 Xl[32 * 136];
    const int tid = threadIdx.x;
    const int n0  = blockIdx.x * 32;
    const int b   = blockIdx.y;
    const int p   = blockIdx.z;
    const float* __restrict__ bias = (p == 0) ? bq : (p == 1) ? bk : bv;

    {   // stage X [n][c] fp16; float4 along contiguous n/hw axis
        const float* src; size_t rs;
        if (p == 0) { const int t = n0 >> 10, hw0 = n0 & 1023;
            src = spatial + (((size_t)(b * 4 + t) * 128) << 10) + hw0; rs = 1024; }
        else { src = temporal + ((size_t)(b * 128) << 12) + n0; rs = 4096; }
        #pragma unroll
        for (int i = 0; i < 2; ++i) {
            const int ii = tid + 256 * i;
            const int c2 = ii >> 3, j = ii & 7;
            const float4 v0 = *(const float4*)(src + (size_t)(2 * c2) * rs + 4 * j);
            const float4 v1 = *(const float4*)(src + (size_t)(2 * c2 + 1) * rs + 4 * j);
            const float a0[4] = {v0.x, v0.y, v0.z, v0.w};
            const float a1[4] = {v1.x, v1.y, v1.z, v1.w};
            #pragma unroll
            for (int u = 0; u < 4; ++u) {
                h2 pk; pk[0] = (_Float16)a0[u]; pk[1] = (_Float16)a1[u];
                *(h2*)&Xl[(4 * j + u) * 136 + 2 * c2] = pk;
            }
        }
    }
    __syncthreads();

    const int w = tid >> 6, lane = tid & 63, n16 = tid & 15, q4 = (tid >> 4) & 3;

    // coalesced fragment-order W loads (1KB/wave per load)
    h8 wf[2][4];
    #pragma unroll
    for (int otl = 0; otl < 2; ++otl)
        #pragma unroll
        for (int ks = 0; ks < 4; ++ks)
            wf[otl][ks] = *(const h8*)(Whf + ((size_t)(((p * 8 + 2 * w + otl) * 4 + ks)) << 9)
                                           + lane * 8);
    h8 xf[2][4];
    #pragma unroll
    for (int ns = 0; ns < 2; ++ns)
        #pragma unroll
        for (int ks = 0; ks < 4; ++ks)
            xf[ns][ks] = *(const h8*)&Xl[(16 * ns + n16) * 136 + 32 * ks + 8 * q4];

    if (p < 2) {
        f4 acc[2][2];
        #pragma unroll
        for (int i = 0; i < 2; ++i) { acc[i][0] = (f4)0.0f; acc[i][1] = (f4)0.0f; }
        #pragma unroll
        for (int otl = 0; otl < 2; ++otl)
            #pragma unroll
            for (int ns = 0; ns < 2; ++ns)
                #pragma unroll
                for (int ks = 0; ks < 4; ++ks)
                    acc[otl][ns] = __builtin_amdgcn_mfma_f32_16x16x32_f16(
                        wf[otl][ks], xf[ns][ks], acc[otl][ns], 0, 0, 0);
        _Float16* __restrict__ dst = (p == 0) ? Qh : Kh;
        #pragma unroll
        for (int otl = 0; otl < 2; ++otl) {
            const float4 bb = *(const float4*)&bias[16 * (2 * w + otl) + 4 * q4];
            #pragma unroll
            for (int ns = 0; ns < 2; ++ns) {
                h4 r;
                r[0]=(_Float16)(acc[otl][ns][0]+bb.x); r[1]=(_Float16)(acc[otl][ns][1]+bb.y);
                r[2]=(_Float16)(acc[otl][ns][2]+bb.z); r[3]=(_Float16)(acc[otl][ns][3]+bb.w);
                *(h4*)(dst + ((size_t)b * NDIM + n0 + 16 * ns + n16) * 128
                           + 16 * (2 * w + otl) + 4 * q4) = r;
            }
        }
    } else {
        f4 acc[2][2];
        #pragma unroll
        for (int i = 0; i < 2; ++i) { acc[i][0] = (f4)0.0f; acc[i][1] = (f4)0.0f; }
        #pragma unroll
        for (int ns = 0; ns < 2; ++ns)
            #pragma unroll
            for (int otl = 0; otl < 2; ++otl)
                #pragma unroll
                for (int ks = 0; ks < 4; ++ks)
                    acc[ns][otl] = __builtin_amdgcn_mfma_f32_16x16x32_f16(
                        xf[ns][ks], wf[otl][ks], acc[ns][otl], 0, 0, 0);
        #pragma unroll
        for (int ns = 0; ns < 2; ++ns)
            #pragma unroll
            for (int otl = 0; otl < 2; ++otl) {
                const float bb = bias[16 * (2 * w + otl) + n16];
                h4 r;
                r[0]=(_Float16)(acc[ns][otl][0]+bb); r[1]=(_Float16)(acc[ns][otl][1]+bb);
                r[2]=(_Float16)(acc[ns][otl][2]+bb); r[3]=(_Float16)(acc[ns][otl][3]+bb);
                *(h4*)(Vt + ((size_t)(b * 128 + 16 * (2 * w + otl) + n16) << 12)
                          + n0 + 16 * ns + 4 * q4) = r;
            }
    }
}

// ---------------- flash attention: R5 tiling + 1-barrier software pipeline ----
// 256 thr / 4 waves (g = q64-group, p = m/c half), m-tile 32, 32 iters.
// LDS double-buffered K/V/P (base offsets computed as integers — no LDS
// pointer arrays, gfx950 rejects their static initializers). 58.4 KB LDS.
__global__ __launch_bounds__(256, 2) void attn_kernel(
    const _Float16* __restrict__ Qh, const _Float16* __restrict__ Kh,
    const _Float16* __restrict__ Vt, _Float16* __restrict__ Opart,
    float* __restrict__ lpart)
{
    __shared__ __align__(16) _Float16 sh[29184];  // K0|K1|V0|V1|P0|P1
    // offsets (h16 units): K: 0 / 4352 ; V: 8704 / 13824 ; P: 18944 / 24064

    const int tid  = threadIdx.x;
    const int w    = tid >> 6, lane = tid & 63;
    const int g    = w >> 1,  p    = w & 1;
    const int n16  = lane & 15, q4 = lane >> 4;
    const int b    = blockIdx.z, hf = blockIdx.y;
    const int n0   = blockIdx.x * 128;
    const int mb   = hf * 1024;

    // Q B-frags: group's q64 (4 strips of 16)
    h8 qf[4][4];
    {
        const _Float16* Qb = Qh + ((size_t)b * NDIM + n0 + 64 * g + n16) * 128;
        #pragma unroll
        for (int qs = 0; qs < 4; ++qs)
            #pragma unroll
            for (int ks = 0; ks < 4; ++ks)
                qf[qs][ks] = *(const h8*)(Qb + (size_t)(16 * qs) * 128 + 32 * ks + 8 * q4);
    }

    // staging maps: K 32x128 (2 int4/thr), V 128x32 (2 int4/thr)
    const int km  = tid >> 4, kc8 = (tid & 15) * 8;
    const int vc  = tid >> 2, vm8 = (tid & 3) * 8;
    const _Float16* kp = Kh + ((size_t)b * NDIM + mb + km) * 128 + kc8;
    const _Float16* vp = Vt + (((size_t)(b * 128 + vc)) << 12) + mb + vm8;

    // prologue: stage K[0] into K-buf 0; prefetch K[1], V[0]
    int4 kreg0 = *(const int4*)kp;
    int4 kreg1 = *(const int4*)(kp + (size_t)16 * 128);
    int4 vreg0 = *(const int4*)vp;
    int4 vreg1 = *(const int4*)(vp + ((size_t)64 << 12));
    *(int4*)&sh[km * 136 + kc8]        = kreg0;
    *(int4*)&sh[(16 + km) * 136 + kc8] = kreg1;
    kp += 32 * 128;
    kreg0 = *(const int4*)kp;
    kreg1 = *(const int4*)(kp + (size_t)16 * 128);

    f4 oacc[4][4];
    #pragma unroll
    for (int i = 0; i < 4; ++i)
        #pragma unroll
        for (int j = 0; j < 4; ++j) oacc[i][j] = (f4)0.0f;
    float lsum[4] = {0.0f, 0.0f, 0.0f, 0.0f};

    for (int it = 0; it < 32; ++it) {
        __syncthreads();   // K[it] staged, P[it-1]/V[it-1] complete, buffers free
        const int cur = it & 1, prv = cur ^ 1;
        _Float16* __restrict__ KB = sh + cur * 4352;
        _Float16* __restrict__ KO = sh + prv * 4352;          // other K buf
        _Float16* __restrict__ VB = sh + 8704  + cur * 5120;
        const _Float16* __restrict__ VP = sh + 8704 + prv * 5120;
        _Float16* __restrict__ Pg = sh + 18944 + cur * 5120 + g * 2560;
        const _Float16* __restrict__ Pp = sh + 18944 + prv * 5120 + g * 2560;

        // ---- PV(it-1): q64 x c64 (c-half p), k = m32
        if (it > 0) {
            h8 pf[4], vf[4];
            #pragma unroll
            for (int qs = 0; qs < 4; ++qs)
                pf[qs] = *(const h8*)&Pp[(16 * qs + n16) * 40 + 8 * q4];
            #pragma unroll
            for (int ct = 0; ct < 4; ++ct)
                vf[ct] = *(const h8*)&VP[(64 * p + 16 * ct + n16) * 40 + 8 * q4];
            #pragma unroll
            for (int qs = 0; qs < 4; ++qs)
                #pragma unroll
                for (int ct = 0; ct < 4; ++ct)
                    oacc[qs][ct] = __builtin_amdgcn_mfma_f32_16x16x32_f16(
                        pf[qs], vf[ct], oacc[qs][ct], 0, 0, 0);
        }

        // ---- S(it): q64 x m16 (m-half p); P = exp(S*scale - 8) -> P[cur]
        {
            f4 sacc[4];
            #pragma unroll
            for (int qs = 0; qs < 4; ++qs) sacc[qs] = (f4)0.0f;
            #pragma unroll
            for (int ks = 0; ks < 4; ++ks) {
                const h8 kf = *(const h8*)&KB[(16 * p + n16) * 136 + 32 * ks + 8 * q4];
                #pragma unroll
                for (int qs = 0; qs < 4; ++qs)
                    sacc[qs] = __builtin_amdgcn_mfma_f32_16x16x32_f16(kf, qf[qs][ks], sacc[qs], 0, 0, 0);
            }
            #pragma unroll
            for (int qs = 0; qs < 4; ++qs) {
                h4 pk;
                #pragma unroll
                for (int r = 0; r < 4; ++r) {
                    const float e = __expf(fmaf(sacc[qs][r], SCALE, -SOFT_BIAS));
                    lsum[qs] += e;
                    pk[r] = (_Float16)e;
                }
                *(h4*)&Pg[(16 * qs + n16) * 40 + 16 * p + 4 * q4] = pk;
            }
        }

        // ---- stage V[it] -> V[cur]; K[it+1] -> K[prv]
        *(int4*)&VB[vc * 40 + vm8]        = vreg0;
        *(int4*)&VB[(64 + vc) * 40 + vm8] = vreg1;
        if (it < 31) {
            *(int4*)&KO[km * 136 + kc8]        = kreg0;
            *(int4*)&KO[(16 + km) * 136 + kc8] = kreg1;
            vp += 32;
            vreg0 = *(const int4*)vp;
            vreg1 = *(const int4*)(vp + ((size_t)64 << 12));
        }
        if (it < 30) {
            kp += 32 * 128;
            kreg0 = *(const int4*)kp;
            kreg1 = *(const int4*)(kp + (size_t)16 * 128);
        }
    }

    // ---- final PV(31): buffers from it=31 (cur=1)
    __syncthreads();
    {
        const _Float16* __restrict__ Pp = sh + 18944 + 5120 + g * 2560;
        const _Float16* __restrict__ VP = sh + 8704  + 5120;
        h8 pf[4], vf[4];
        #pragma unroll
        for (int qs = 0; qs < 4; ++qs)
            pf[qs] = *(const h8*)&Pp[(16 * qs + n16) * 40 + 8 * q4];
        #pragma unroll
        for (int ct = 0; ct < 4; ++ct)
            vf[ct] = *(const h8*)&VP[(64 * p + 16 * ct + n16) * 40 + 8 * q4];
        #pragma unroll
        for (int qs = 0; qs < 4; ++qs)
            #pragma unroll
            for (int ct = 0; ct < 4; ++ct)
                oacc[qs][ct] = __builtin_amdgcn_mfma_f32_16x16x32_f16(
                    pf[qs], vf[ct], oacc[qs][ct], 0, 0, 0);
    }

    // ---- l: reduce q4 replicas; store per-(hf,p) partial
    #pragma unroll
    for (int qs = 0; qs < 4; ++qs) {
        lsum[qs] += __shfl_xor(lsum[qs], 16, 64);
        lsum[qs] += __shfl_xor(lsum[qs], 32, 64);
    }
    if (q4 == 0) {
        float* lb = lpart + ((size_t)((hf * 2 + p) * 4 + b)) * NDIM + n0 + 64 * g;
        #pragma unroll
        for (int qs = 0; qs < 4; ++qs) lb[16 * qs + n16] = lsum[qs];
    }

    // ---- epilogue: full 128-row transpose via LDS (reuse sh), coalesced stores
    __syncthreads();
    #pragma unroll
    for (int qs = 0; qs < 4; ++qs)
        #pragma unroll
        for (int ct = 0; ct < 4; ++ct)
            #pragma unroll
            for (int r = 0; r < 4; ++r)
                sh[(64 * g + 16 * qs + 4 * q4 + r) * 136 + 64 * p + 16 * ct + n16] =
                    (_Float16)oacc[qs][ct][r];
    __syncthreads();
    const size_t ob = ((size_t)(hf * 4 + b) * NDIM + n0) * 128;
    #pragma unroll
    for (int i = 0; i < 8; ++i) {
        const int ii  = tid + 256 * i;
        const int row = ii >> 4, c8 = (ii & 15) * 8;
        *(int4*)(Opart + ob + (size_t)row * 128 + c8) = *(const int4*)&sh[row * 136 + c8];
    }
}

// ---------------- final projection: merge 8 partials, /l, Wo, out[b][c][n] ----
__global__ __launch_bounds__(256, 2) void proj_final_kernel(
    const _Float16* __restrict__ Opart, const float* __restrict__ lpart,
    const _Float16* __restrict__ Whf, const float* __restrict__ bo,
    float* __restrict__ out)
{
    __shared__ __align__(16) _Float16 Xl[32 * 136];
    __shared__ float lrow[32];
    __shared__ __align__(16) float Ofin[128 * 36];
    const int tid = threadIdx.x;
    const int n0  = blockIdx.x * 32;
    const int b   = blockIdx.y;

    if (tid < 32) {
        float l = 0.0f;
        #pragma unroll
        for (int h8i = 0; h8i < 8; ++h8i)
            l += lpart[((size_t)(h8i * 4 + b)) * NDIM + n0 + tid];
        lrow[tid] = 1.0f / l;
    }
    float vals[2][8];
    int rows[2], c8s[2];
    #pragma unroll
    for (int i = 0; i < 2; ++i) {
        const int ii = tid + 256 * i;
        rows[i] = ii >> 4; c8s[i] = (ii & 15) * 8;
        #pragma unroll
        for (int j = 0; j < 8; ++j) vals[i][j] = 0.0f;
        #pragma unroll
        for (int hf = 0; hf < 4; ++hf) {
            const h8 o = *(const h8*)(Opart + ((size_t)(hf * 4 + b) * NDIM + n0 + rows[i]) * 128
                                      + c8s[i]);
            #pragma unroll
            for (int j = 0; j < 8; ++j) vals[i][j] += (float)o[j];
        }
    }
    __syncthreads();
    #pragma unroll
    for (int i = 0; i < 2; ++i) {
        const float linv = lrow[rows[i]];
        h8 r;
        #pragma unroll
        for (int j = 0; j < 8; ++j) r[j] = (_Float16)(vals[i][j] * linv);
        *(h8*)&Xl[rows[i] * 136 + c8s[i]] = r;
    }
    __syncthreads();

    const int w = tid >> 6, lane = tid & 63, n16 = tid & 15, q4 = (tid >> 4) & 3;

    h8 wf[2][4];
    #pragma unroll
    for (int otl = 0; otl < 2; ++otl)
        #pragma unroll
        for (int ks = 0; ks < 4; ++ks)
            wf[otl][ks] = *(const h8*)(Whf + ((size_t)(((3 * 8 + 2 * w + otl) * 4 + ks)) << 9)
                                           + lane * 8);
    h8 xf[2][4];
    #pragma unroll
    for (int ns = 0; ns < 2; ++ns)
        #pragma unroll
        for (int ks = 0; ks < 4; ++ks)
            xf[ns][ks] = *(const h8*)&Xl[(16 * ns + n16) * 136 + 32 * ks + 8 * q4];

    f4 acc[2][2];
    #pragma unroll
    for (int i = 0; i < 2; ++i) { acc[i][0] = (f4)0.0f; acc[i][1] = (f4)0.0f; }
    #pragma unroll
    for (int otl = 0; otl < 2; ++otl)
        #pragma unroll
        for (int ns = 0; ns < 2; ++ns)
            #pragma unroll
            for (int ks = 0; ks < 4; ++ks)
                acc[otl][ns] = __builtin_amdgcn_mfma_f32_16x16x32_f16(
                    wf[otl][ks], xf[ns][ks], acc[otl][ns], 0, 0, 0);

    #pragma unroll
    for (int otl = 0; otl < 2; ++otl) {
        const float4 bb = *(const float4*)&bo[16 * (2 * w + otl) + 4 * q4];
        const float bias[4] = {bb.x, bb.y, bb.z, bb.w};
        #pragma unroll
        for (int ns = 0; ns < 2; ++ns)
            #pragma unroll
            for (int r = 0; r < 4; ++r)
                Ofin[(16 * (2 * w + otl) + 4 * q4 + r) * 36 + 16 * ns + n16] =
                    acc[otl][ns][r] + bias[r];
    }
    __syncthreads();
    #pragma unroll
    for (int i = 0; i < 4; ++i) {
        const int ii  = tid + 256 * i;
        const int row = ii >> 3, j = ii & 7;
        *(float4*)(out + (((size_t)(b * 128 + row)) << 12) + n0 + 4 * j) =
            *(const float4*)&Ofin[row * 36 + 4 * j];
    }
}

extern "C" void kernel_launch(void* const* d_in, const int* in_sizes, int n_in,
                              void* d_out, int out_size, void* d_ws, size_t ws_size,
                              hipStream_t stream)
{
    const float* spatial  = (const float*)d_in[0];
    const float* temporal = (const float*)d_in[1];
    const float* Wq = (const float*)d_in[2];
    const float* bq = (const float*)d_in[3];
    const float* Wk = (const float*)d_in[4];
    const float* bk = (const float*)d_in[5];
    const float* Wv = (const float*)d_in[6];
    const float* bv = (const float*)d_in[7];
    const float* Wo = (const float*)d_in[8];
    const float* bo = (const float*)d_in[9];

    char* ws = (char*)d_ws;                               // 28.63 MB total
    _Float16* Qh    = (_Float16*)(ws);                    //  4 MB [b][n][c]
    _Float16* Kh    = (_Float16*)(ws + (4u  << 20));      //  4 MB [b][n][c]
    _Float16* Vt    = (_Float16*)(ws + (8u  << 20));      //  4 MB [b][c][n]
    _Float16* Opart = (_Float16*)(ws + (12u << 20));      // 16 MB [hf][b][n][c]
    float*    lpart = (float*)   (ws + (28u << 20));      // 512 KB [hf*2+p][b][n]
    _Float16* Whf   = (_Float16*)(ws + (28u << 20) + (512u << 10)); // 128 KB frag-order

    prep_w_kernel<<<32, 256, 0, stream>>>(Wq, Wk, Wv, Wo, Whf);
    proj_qkv_kernel<<<dim3(128, 4, 3), 256, 0, stream>>>(
        spatial, temporal, Whf, bq, bk, bv, Qh, Kh, Vt);
    attn_kernel<<<dim3(32, 4, 4), 256, 0, stream>>>(Qh, Kh, Vt, Opart, lpart);
    proj_final_kernel<<<dim3(128, 4), 256, 0, stream>>>(Opart, lpart, Whf, bo,
                                                        (float*)d_out);
}